// Round 7
// baseline (31.281 us; speedup 1.0000x reference)
//
#include <hip/hip_runtime.h>
#include <math.h>

#define BSZ 320
#define N2  640
#define DIM 128
#define GAM (1.0/0.07)

__device__ __forceinline__ double wave_red(double v) {
    #pragma unroll
    for (int off = 32; off > 0; off >>= 1) v += __shfl_down(v, off, 64);
    return v;
}

// --- K0: normalize rows (f64 norm -> f32 zn); zero K2's ticket counter ---
__launch_bounds__(128)
__global__ void k_prep(const float* __restrict__ z, float* __restrict__ zn,
                       int* __restrict__ counter) {
    const int row = blockIdx.x, k = threadIdx.x;   // 640 x 128
    if (row == 0 && k == 0) *counter = 0;
    double v = (double)z[row * DIM + k];
    __shared__ double s2[2];
    double w = wave_red(v * v);
    int wave = k >> 6, lane = k & 63;
    if (lane == 0) s2[wave] = w;
    __syncthreads();
    zn[row * DIM + k] = (float)(v / sqrt(s2[0] + s2[1]));
}

// --- K1: gram. Grid (160,2): x = row-pair i0, y = j-half. 320 threads.
// jh=0: E rows (zero diag) + rE/ssq.  jh=1: KnT scatter. All-f32 inner loop. ---
__launch_bounds__(320)
__global__ void k_gram(const float* __restrict__ zn, double* __restrict__ E,
                       double* __restrict__ KnT, double* __restrict__ rE,
                       double* __restrict__ ssq) {
    const int tid = threadIdx.x;           // 320
    const int i0  = blockIdx.x * 2;        // 160
    const int jh  = blockIdx.y;            // 2
    __shared__ float  zc[320][36];         // 32-k chunk of this half's 320 rows
    __shared__ float  zi[2][128];
    __shared__ double sE[2][5], sQ[2][5];

    if (tid < 256) {
        int r = tid >> 7, k = tid & 127;
        zi[r][k] = zn[(i0 + r) * DIM + k];
    }

    float cr0 = 0.f, cr1 = 0.f;
    for (int kc = 0; kc < 4; kc++) {
        const int k0 = kc * 32;
        __syncthreads();                   // zc reuse guard (covers zi on kc=0)
        #pragma unroll
        for (int it = 0; it < 8; it++) {
            int f = it * 320 + tid;        // 0..2559
            int row = f >> 3, c4 = f & 7;
            *(float4*)&zc[row][c4 * 4] =
                *(const float4*)(zn + (jh * 320 + row) * DIM + k0 + c4 * 4);
        }
        __syncthreads();
        #pragma unroll
        for (int k4 = 0; k4 < 8; k4++) {
            float4 b  = *(const float4*)&zc[tid][k4 * 4];      // stride-36: bank-clean
            float4 a0 = *(const float4*)&zi[0][k0 + k4 * 4];   // broadcast
            float4 a1 = *(const float4*)&zi[1][k0 + k4 * 4];   // broadcast
            cr0 = fmaf(a0.x, b.x, cr0); cr1 = fmaf(a1.x, b.x, cr1);
            cr0 = fmaf(a0.y, b.y, cr0); cr1 = fmaf(a1.y, b.y, cr1);
            cr0 = fmaf(a0.z, b.z, cr0); cr1 = fmaf(a1.z, b.z, cr1);
            cr0 = fmaf(a0.w, b.w, cr0); cr1 = fmaf(a1.w, b.w, cr1);
        }
    }
    double v0 = exp(-GAM * (2.0 - 2.0 * (double)cr0));
    double v1 = exp(-GAM * (2.0 - 2.0 * (double)cr1));
    const int wave = tid >> 6, lane = tid & 63;
    if (jh == 0) {
        double e0 = (tid == i0    ) ? 0.0 : v0;
        double e1 = (tid == i0 + 1) ? 0.0 : v1;
        E[(i0    ) * BSZ + tid] = e0;
        E[(i0 + 1) * BSZ + tid] = e1;
        double q0 = e0 * e0, q1 = e1 * e1;
        e0 = wave_red(e0); q0 = wave_red(q0);
        e1 = wave_red(e1); q1 = wave_red(q1);
        if (lane == 0) { sE[0][wave] = e0; sQ[0][wave] = q0;
                         sE[1][wave] = e1; sQ[1][wave] = q1; }
        __syncthreads();
        if (tid < 2) {
            double se = 0.0, sq = 0.0;
            for (int w = 0; w < 5; w++) { se += sE[tid][w]; sq += sQ[tid][w]; }
            rE[i0 + tid] = se; ssq[i0 + tid] = sq;
        }
    } else {
        KnT[tid * BSZ + i0]     = v0;      // KnT[j'][i] = K[i, 320+j']
        KnT[tid * BSZ + i0 + 1] = v1;
    }
}

// --- K2: per-t coef + final pass; non-atomic partials + ticket; last block outputs ---
__launch_bounds__(320)
__global__ void k_cf(const double* __restrict__ E, const double* __restrict__ KnT,
                     const double* __restrict__ rE, const double* __restrict__ ssq,
                     double* __restrict__ partials, int* __restrict__ counter,
                     float* __restrict__ out) {
    const int t = blockIdx.x, tid = threadIdx.x;   // 320 x 320
    const int wave = tid >> 6, lane = tid & 63;
    __shared__ double sred[5][7];
    __shared__ double sc[8];
    __shared__ int lastflag;
    const double a = 1.0 / 1.1, c = 1.0 / 321.1;
    const double q = 1.0 - 320.0 * c;

    double rEi  = rE[tid];
    double Ereg = E[t * BSZ + tid];
    double kn   = KnT[t * BSZ + tid];
    if (tid == t) sc[6] = kn;                      // posterm_t = K[t, 320+t]

    // block reduce: S = sum rE, mv = E[t,:].rE
    {
        double s1 = wave_red(rEi);
        double s2 = wave_red(Ereg * rEi);
        if (lane == 0) { sred[wave][0] = s1; sred[wave][1] = s2; }
    }
    __syncthreads();
    if (tid == 0) {
        double S = 0, mv = 0;
        for (int w = 0; w < 5; w++) { S += sred[w][0]; mv += sred[w][1]; }
        double rEt = rE[t], ssqt = ssq[t];
        double pt  = a * q - a * a * q * (rEt - c * S);
        double b   = 320.0 * a * q - a * a * q * q * S;
        double up  = a * q * rEt - a * a * q * (mv - c * S * rEt);
        double sc1 = a * ssqt - a * c * rEt * rEt;
        double Wtt = -a * c * rEt;
        double Mtt = a * (1.0 - c) - a * a * (c * c * S - 2.0 * c * rEt);
        double s11 = 1.0 - up, s12 = -b, s21 = -sc1, s22 = 1.0 - up;
        double det = s11 * s22 - s12 * s21;
        double r1 = 2.0 * b, r2 = 2.0 * up;
        double be1 = (s22 * r1 - s12 * r2) / det;
        double be2 = (s11 * r2 - s21 * r1) / det;
        double g1  = (s22 * pt - s12 * Wtt) / det;
        double g2  = (s11 * Wtt - s21 * pt) / det;
        double ytt = 2.0 * pt + be1 * Wtt + be2 * pt;
        double dt  = Mtt + g1 * Wtt + g2 * pt;
        double rho = ytt / dt;
        sc[0] = rEt;
        sc[1] = S;
        sc[2] = 2.0 + be2 - rho * g2;   // cP
        sc[3] = be1 - rho * g1;         // cW
        sc[4] = -rho;                   // cM
    }
    __syncthreads();

    // final per-(t, i=tid) pass
    {
        double rEt = sc[0], S = sc[1], cP = sc[2], cW = sc[3], cM = sc[4];
        double s_neg = 0, s_al = 0, s_kn = 0, cz = 0, c1v = 0, cpos = 0;
        if (tid != t) {
            double p_i = a * q - a * a * q * (rEi - c * S);
            double V   = a * Ereg - a * c * rEt;
            double Mi  = -a * c - a * a * (Ereg - c * (rEt + rEi) + c * c * S);
            double x = cP * p_i + cW * V + cM * Mi;
            double alpha = fmin(fmax(x, 0.0), 1.0);
            s_neg = alpha * kn; s_al = alpha; s_kn = kn;
            cz   = (x <= 0.0) ? 1.0 : 0.0;
            c1v  = (x >= 1.0) ? 1.0 : 0.0;
            cpos = (x > 0.0) ? 1.0 : 0.0;
        }
        s_neg = wave_red(s_neg); s_al = wave_red(s_al); s_kn = wave_red(s_kn);
        cz = wave_red(cz); c1v = wave_red(c1v); cpos = wave_red(cpos);
        if (lane == 0) {
            sred[wave][0] = s_neg; sred[wave][1] = s_al; sred[wave][2] = s_kn;
            sred[wave][3] = cz;    sred[wave][4] = c1v;  sred[wave][5] = cpos;
        }
    }
    __syncthreads();
    if (tid == 0) {
        double a0 = 0, a1 = 0, a2 = 0, a3 = 0, a4 = 0, a5 = 0;
        for (int w = 0; w < 5; w++) {
            a0 += sred[w][0]; a1 += sred[w][1]; a2 += sred[w][2];
            a3 += sred[w][3]; a4 += sred[w][4]; a5 += sred[w][5];
        }
        partials[t * 8 + 0] = a0;
        partials[t * 8 + 1] = a1 * sc[6];
        partials[t * 8 + 2] = a2;
        partials[t * 8 + 3] = a3;
        partials[t * 8 + 4] = a4;
        partials[t * 8 + 5] = a5;
        partials[t * 8 + 6] = sc[6];
        __threadfence();
        int ticket = atomicAdd(counter, 1);
        lastflag = (ticket == BSZ - 1) ? 1 : 0;
    }
    __syncthreads();

    // last block: global reduce of partials -> 6 f32 outputs
    if (lastflag) {
        __threadfence();
        double v0 = partials[tid * 8 + 0], v1 = partials[tid * 8 + 1];
        double v2 = partials[tid * 8 + 2], v3 = partials[tid * 8 + 3];
        double v4 = partials[tid * 8 + 4], v5 = partials[tid * 8 + 5];
        double v6 = partials[tid * 8 + 6];
        v0 = wave_red(v0); v1 = wave_red(v1); v2 = wave_red(v2);
        v3 = wave_red(v3); v4 = wave_red(v4); v5 = wave_red(v5);
        v6 = wave_red(v6);
        if (lane == 0) {
            sred[wave][0] = v0; sred[wave][1] = v1; sred[wave][2] = v2;
            sred[wave][3] = v3; sred[wave][4] = v4; sred[wave][5] = v5;
            sred[wave][6] = v6;
        }
        __syncthreads();
        if (tid == 0) {
            double b0 = 0, b1 = 0, b2 = 0, b3 = 0, b4 = 0, b5 = 0, b6 = 0;
            for (int w = 0; w < 5; w++) {
                b0 += sred[w][0]; b1 += sred[w][1]; b2 += sred[w][2];
                b3 += sred[w][3]; b4 += sred[w][4]; b5 += sred[w][5];
                b6 += sred[w][6];
            }
            out[0] = (float)((b0 - b1) / 320.0);        // loss
            out[1] = (float)(b6 / 320.0);               // pos_terms.mean()
            out[2] = (float)(b2 / (319.0 * 320.0));     // Kn.mean()
            out[3] = (float)(b4 / (b5 + 1e-10));        // sparsity
            out[4] = (float)(b3 / (320.0 * 319.0));     // num_zero
            out[5] = 0.0f;
        }
    }
}

extern "C" void kernel_launch(void* const* d_in, const int* in_sizes, int n_in,
                              void* d_out, int out_size, void* d_ws, size_t ws_size,
                              hipStream_t stream) {
    const float* z = (const float*)d_in[0];
    float* out = (float*)d_out;
    double* ws = (double*)d_ws;

    double* E        = ws;                 // 102400 f64
    double* KnT      = E + 102400;         // 102400 f64
    double* rE       = KnT + 102400;       // 320
    double* ssq      = rE + 320;           // 320
    double* partials = ssq + 320;          // 320*8
    int*    counter  = (int*)(partials + 320 * 8);
    float*  zn       = (float*)(counter + 16);   // 81920 f32

    k_prep<<<dim3(N2), dim3(DIM), 0, stream>>>(z, zn, counter);
    k_gram<<<dim3(BSZ / 2, 2), dim3(BSZ), 0, stream>>>(zn, E, KnT, rE, ssq);
    k_cf  <<<dim3(BSZ), dim3(BSZ), 0, stream>>>(E, KnT, rE, ssq, partials, counter, out);
}